// Round 1
// baseline (7805.738 us; speedup 1.0000x reference)
//
#include <hip/hip_runtime.h>
#include <hip/hip_bf16.h>

typedef __hip_bfloat16 bf16;

#define TS    48            // sequence length / spatial dim
#define CDIM  128           // channels
#define YZ    (48*48)
#define XYZ   (48*48*48)
#define PAD   130           // bf16 LDS row stride (65 words, odd -> conflict-free columns)
#define FPAD  129           // fp32 LDS row stride (odd -> conflict-free columns)
#define A_ELEMS 28311552ull // 2*128*48^3

// ---------------- weight transpose + cast: dst[c*R + r] = src[r*128 + c] -------------
__global__ void transpose_w_bf16(const float* __restrict__ src, bf16* __restrict__ dst, int R) {
    int idx = blockIdx.x * blockDim.x + threadIdx.x;
    if (idx < R * 128) {
        int r = idx >> 7;
        int c = idx & 127;
        dst[c * R + r] = __float2bfloat16(src[r * 128 + c]);
    }
}

// ---------------- axial attention: one block = one 48-token sequence ------------------
// AXIS: 0 -> attend along X (weights set 0), 1 -> Y (set 1), 2 -> Z (set 2)
template<int AXIS>
__global__ __launch_bounds__(256, 2)
void attn_axis(const float* __restrict__ x,
               const float* __restrict__ px, const float* __restrict__ py,
               const float* __restrict__ pz,
               const bf16* __restrict__ wqT, const bf16* __restrict__ wkvT,
               const bf16* __restrict__ woutT, const float* __restrict__ bout,
               float* __restrict__ A, int accumulate)
{
    __shared__ bf16 xf[TS * PAD];   // x2 tile, later reused for attention output o
    __shared__ bf16 qs[TS * PAD];
    __shared__ bf16 ks[TS * PAD];
    __shared__ bf16 vs[TS * PAD];
    __shared__ float sc[TS * 49];   // per-head scores (fp32)

    const int s   = blockIdx.x;
    const int b   = s / YZ;
    const int rr  = s % YZ;
    const int u   = rr / TS;
    const int v   = rr % TS;
    const int tid = threadIdx.x;

    // ---- stage x2 = 2x + px + py + pz into LDS (bf16) ----
    for (int f = tid; f < TS * CDIM; f += 256) {
        const int c = f / TS;
        const int t = f % TS;
        int xx, yy, zz;
        if (AXIS == 0)      { xx = t; yy = u; zz = v; }
        else if (AXIS == 1) { xx = u; yy = t; zz = v; }
        else                { xx = u; yy = v; zz = t; }
        const float pos = px[c * TS + xx] + py[c * TS + yy] + pz[c * TS + zz];
        const float val = 2.0f * x[(size_t)(b * CDIM + c) * XYZ + xx * YZ + yy * TS + zz] + pos;
        xf[t * PAD + c] = __float2bfloat16(val);
    }
    __syncthreads();

    const int j    = tid & 127;
    const int half = tid >> 7;

    // ---- q / k / v projections (fp32 accumulate) ----
    for (int i = half; i < TS; i += 2) {
        float aq = 0.f, ak = 0.f, av = 0.f;
        #pragma unroll 8
        for (int c = 0; c < CDIM; ++c) {
            const float xc = __bfloat162float(xf[i * PAD + c]);
            aq += xc * __bfloat162float(wqT[c * 128 + j]);
            ak += xc * __bfloat162float(wkvT[c * 256 + j]);
            av += xc * __bfloat162float(wkvT[c * 256 + 128 + j]);
        }
        qs[i * PAD + j] = __float2bfloat16(aq);
        ks[i * PAD + j] = __float2bfloat16(ak);
        vs[i * PAD + j] = __float2bfloat16(av);
    }
    __syncthreads();

    // ---- per-head attention ----
    for (int h = 0; h < 8; ++h) {
        const int hb = h * 16;
        for (int f = tid; f < TS * TS; f += 256) {
            const int i  = f / TS;
            const int jj = f % TS;
            float acc = 0.f;
            #pragma unroll
            for (int e = 0; e < 16; ++e)
                acc += __bfloat162float(qs[i * PAD + hb + e]) *
                       __bfloat162float(ks[jj * PAD + hb + e]);
            sc[i * 49 + jj] = acc * 0.25f;   // e^-0.5, e=16
        }
        __syncthreads();
        if (tid < TS) {
            const int i = tid;
            float m = -1e30f;
            for (int jj = 0; jj < TS; ++jj) m = fmaxf(m, sc[i * 49 + jj]);
            float ssum = 0.f;
            for (int jj = 0; jj < TS; ++jj) {
                const float e = __expf(sc[i * 49 + jj] - m);
                sc[i * 49 + jj] = e;
                ssum += e;
            }
            const float inv = 1.0f / ssum;
            for (int jj = 0; jj < TS; ++jj) sc[i * 49 + jj] *= inv;
        }
        __syncthreads();
        for (int f = tid; f < TS * 16; f += 256) {
            const int i = f >> 4;
            const int e = f & 15;
            float acc = 0.f;
            #pragma unroll 8
            for (int jj = 0; jj < TS; ++jj)
                acc += sc[i * 49 + jj] * __bfloat162float(vs[jj * PAD + hb + e]);
            xf[i * PAD + hb + e] = __float2bfloat16(acc);  // xf now holds o
        }
        __syncthreads();
    }

    // ---- output projection, accumulate into channels-last A ----
    for (int i = half; i < TS; i += 2) {
        float acc = 0.f;
        #pragma unroll 8
        for (int c = 0; c < CDIM; ++c)
            acc += __bfloat162float(xf[i * PAD + c]) * __bfloat162float(woutT[c * 128 + j]);
        acc += bout[j];
        int xx, yy, zz;
        if (AXIS == 0)      { xx = i; yy = u; zz = v; }
        else if (AXIS == 1) { xx = u; yy = i; zz = v; }
        else                { xx = u; yy = v; zz = i; }
        const size_t tok = ((size_t)(b * TS + xx) * TS + yy) * TS + zz;
        if (accumulate) A[tok * 128 + j] += acc;
        else            A[tok * 128 + j] = acc;
    }
}

// ---------------- residual + LN1 + MLP + LN2 + transpose-out: one block = one z-line ---
__global__ __launch_bounds__(256, 2)
void mlp_ln(const float* __restrict__ x,
            const float* __restrict__ px, const float* __restrict__ py,
            const float* __restrict__ pz,
            const float* __restrict__ A,
            const float* __restrict__ ln_g, const float* __restrict__ ln_b,
            const bf16* __restrict__ w1T, const float* __restrict__ b1,
            const bf16* __restrict__ w2T, const float* __restrict__ b2,
            float* __restrict__ out)
{
    __shared__ float xr[TS * FPAD];   // fp32: residual input, later MLP2 output
    __shared__ bf16  lnb[TS * PAD];   // LN1 output (also the inner residual)
    __shared__ bf16  hb[TS * PAD];    // relu hidden
    __shared__ float gs[128], bs[128], b1s[128], b2s[128];
    __shared__ float mean_[TS], rstd_[TS];

    const int s   = blockIdx.x;
    const int b   = s / YZ;
    const int rr  = s % YZ;
    const int xx  = rr / TS;
    const int yy  = rr % TS;
    const int tid = threadIdx.x;

    if (tid < 128) {
        gs[tid]  = ln_g[tid];
        bs[tid]  = ln_b[tid];
        b1s[tid] = b1[tid];
        b2s[tid] = b2[tid];
    }

    const size_t tokbase = ((size_t)(b * TS + xx) * TS + yy) * TS;  // + z

    // attention sum (channels-last, fully contiguous tile)
    for (int f = tid; f < TS * CDIM; f += 256) {
        const int t = f >> 7;
        const int c = f & 127;
        xr[t * FPAD + c] = A[tokbase * 128 + f];
    }
    __syncthreads();
    // + x2 (recomputed fp32-exact from pristine x)
    for (int f = tid; f < TS * CDIM; f += 256) {
        const int c = f / TS;
        const int z = f % TS;
        const float val = 2.0f * x[(size_t)(b * CDIM + c) * XYZ + xx * YZ + yy * TS + z]
                        + px[c * TS + xx] + py[c * TS + yy] + pz[c * TS + z];
        xr[z * FPAD + c] += val;
    }
    __syncthreads();

    // LN1 stats
    if (tid < TS) {
        float m = 0.f;
        for (int c = 0; c < CDIM; ++c) m += xr[tid * FPAD + c];
        m *= (1.0f / CDIM);
        float vv = 0.f;
        for (int c = 0; c < CDIM; ++c) { const float d = xr[tid * FPAD + c] - m; vv += d * d; }
        vv *= (1.0f / CDIM);
        mean_[tid] = m;
        rstd_[tid] = rsqrtf(vv + 1e-5f);
    }
    __syncthreads();
    for (int f = tid; f < TS * CDIM; f += 256) {
        const int t = f >> 7;
        const int c = f & 127;
        lnb[t * PAD + c] = __float2bfloat16((xr[t * FPAD + c] - mean_[t]) * rstd_[t] * gs[c] + bs[c]);
    }
    __syncthreads();

    const int j    = tid & 127;
    const int half = tid >> 7;

    // MLP layer 1 + relu
    for (int i = half; i < TS; i += 2) {
        float acc = 0.f;
        #pragma unroll 8
        for (int c = 0; c < CDIM; ++c)
            acc += __bfloat162float(lnb[i * PAD + c]) * __bfloat162float(w1T[c * 128 + j]);
        hb[i * PAD + j] = __float2bfloat16(fmaxf(acc + b1s[j], 0.f));
    }
    __syncthreads();
    // MLP layer 2 + inner residual
    for (int i = half; i < TS; i += 2) {
        float acc = 0.f;
        #pragma unroll 8
        for (int c = 0; c < CDIM; ++c)
            acc += __bfloat162float(hb[i * PAD + c]) * __bfloat162float(w2T[c * 128 + j]);
        xr[i * FPAD + j] = acc + b2s[j] + __bfloat162float(lnb[i * PAD + j]);
    }
    __syncthreads();

    // LN2 stats
    if (tid < TS) {
        float m = 0.f;
        for (int c = 0; c < CDIM; ++c) m += xr[tid * FPAD + c];
        m *= (1.0f / CDIM);
        float vv = 0.f;
        for (int c = 0; c < CDIM; ++c) { const float d = xr[tid * FPAD + c] - m; vv += d * d; }
        vv *= (1.0f / CDIM);
        mean_[tid] = m;
        rstd_[tid] = rsqrtf(vv + 1e-5f);
    }
    __syncthreads();

    // write channels-first output (48-contiguous runs per channel)
    for (int f = tid; f < TS * CDIM; f += 256) {
        const int c = f / TS;
        const int z = f % TS;
        const float val = (xr[z * FPAD + c] - mean_[z]) * rstd_[z] * gs[c] + bs[c];
        out[(size_t)(b * CDIM + c) * XYZ + xx * YZ + yy * TS + z] = val;
    }
}

// -------------------------------------------------------------------------------------
extern "C" void kernel_launch(void* const* d_in, const int* in_sizes, int n_in,
                              void* d_out, int out_size, void* d_ws, size_t ws_size,
                              hipStream_t stream)
{
    const float* x    = (const float*)d_in[0];
    const float* px   = (const float*)d_in[1];
    const float* py   = (const float*)d_in[2];
    const float* pz   = (const float*)d_in[3];
    const float* wq[3]   = { (const float*)d_in[4],  (const float*)d_in[8],  (const float*)d_in[12] };
    const float* wkv[3]  = { (const float*)d_in[5],  (const float*)d_in[9],  (const float*)d_in[13] };
    const float* wout[3] = { (const float*)d_in[6],  (const float*)d_in[10], (const float*)d_in[14] };
    const float* bout[3] = { (const float*)d_in[7],  (const float*)d_in[11], (const float*)d_in[15] };
    const float* ln_g = (const float*)d_in[16];
    const float* ln_b = (const float*)d_in[17];
    const float* w1   = (const float*)d_in[18];
    const float* b1   = (const float*)d_in[19];
    const float* w2   = (const float*)d_in[20];
    const float* b2   = (const float*)d_in[21];
    float* out = (float*)d_out;

    // workspace layout: A (fp32, 113.25 MB) | transposed bf16 weights (~450 KB)
    float* A  = (float*)d_ws;
    bf16*  wb = (bf16*)((char*)d_ws + A_ELEMS * sizeof(float));
    bf16* wqT[3]   = { wb,          wb + 16384,  wb + 32768 };
    bf16* wkvT[3]  = { wb + 49152,  wb + 81920,  wb + 114688 };
    bf16* woutT[3] = { wb + 147456, wb + 163840, wb + 180224 };
    bf16* w1T = wb + 196608;
    bf16* w2T = wb + 212992;

    // ---- weight prep ----
    for (int a = 0; a < 3; ++a) {
        transpose_w_bf16<<<(16384 + 255) / 256, 256, 0, stream>>>(wq[a],   wqT[a],   128);
        transpose_w_bf16<<<(32768 + 255) / 256, 256, 0, stream>>>(wkv[a],  wkvT[a],  256);
        transpose_w_bf16<<<(16384 + 255) / 256, 256, 0, stream>>>(wout[a], woutT[a], 128);
    }
    transpose_w_bf16<<<(16384 + 255) / 256, 256, 0, stream>>>(w1, w1T, 128);
    transpose_w_bf16<<<(16384 + 255) / 256, 256, 0, stream>>>(w2, w2T, 128);

    // ---- three axial attentions, accumulating into A ----
    const int nseq = 2 * YZ;  // 4608
    attn_axis<0><<<nseq, 256, 0, stream>>>(x, px, py, pz, wqT[0], wkvT[0], woutT[0], bout[0], A, 0);
    attn_axis<1><<<nseq, 256, 0, stream>>>(x, px, py, pz, wqT[1], wkvT[1], woutT[1], bout[1], A, 1);
    attn_axis<2><<<nseq, 256, 0, stream>>>(x, px, py, pz, wqT[2], wkvT[2], woutT[2], bout[2], A, 1);

    // ---- residual + LN + MLP + LN + transpose out ----
    mlp_ln<<<nseq, 256, 0, stream>>>(x, px, py, pz, A, ln_g, ln_b, w1T, b1, w2T, b2, out);
}

// Round 2
// 938.152 us; speedup vs baseline: 8.3203x; 8.3203x over previous
//
#include <hip/hip_runtime.h>
#include <hip/hip_bf16.h>

typedef __attribute__((ext_vector_type(8))) short short8;
typedef __attribute__((ext_vector_type(4))) short short4v;
typedef __attribute__((ext_vector_type(4))) float floatx4;

#define XSTR 136   // bf16 [t][c] tile stride (272B: 16B-aligned rows, 2-way banks)
#define VSTR 56    // bf16 [c][t] transposed-V / P stride (112B aligned)
#define SSTR 132   // fp32 stage stride (528B aligned)

static __device__ __forceinline__ short f2b(float f) {
    __hip_bfloat16 h = __float2bfloat16(f);
    return *reinterpret_cast<short*>(&h);
}
static __device__ __forceinline__ float b2f(short s) {
    unsigned int u = ((unsigned int)(unsigned short)s) << 16;
    return __uint_as_float(u);
}

// ---------------- weight cast (keeps [n][k] row-major = MFMA B-operand layout) -------
// dst layout (shorts): [a=0..2: wq_a 16384 | wkv_a 32768] (=49152 each)
//                      | wout0,1,2 (16384 each) | w1 | w2
__global__ __launch_bounds__(256) void prep_weights(
    const float* __restrict__ wq0, const float* __restrict__ wkv0,
    const float* __restrict__ wq1, const float* __restrict__ wkv1,
    const float* __restrict__ wq2, const float* __restrict__ wkv2,
    const float* __restrict__ wout0, const float* __restrict__ wout1,
    const float* __restrict__ wout2, const float* __restrict__ w1,
    const float* __restrict__ w2, short* __restrict__ dst)
{
    const int g = blockIdx.x * 256 + threadIdx.x;  // grid exactly covers 229376
    const float* wqs[3]  = { wq0, wq1, wq2 };
    const float* wkvs[3] = { wkv0, wkv1, wkv2 };
    const float* rest[5] = { wout0, wout1, wout2, w1, w2 };
    float val;
    if (g < 147456) {
        const int a = g / 49152, l = g % 49152;
        val = (l < 16384) ? wqs[a][l] : wkvs[a][l - 16384];
    } else {
        const int l = g - 147456;
        val = rest[l >> 14][l & 16383];
    }
    dst[g] = f2b(val);
}

// ---------------- x2 = 2x + px + py + pz, channels-last bf16 -------------------------
__global__ __launch_bounds__(256) void prep_x2(
    const float* __restrict__ x, const float* __restrict__ px,
    const float* __restrict__ py, const float* __restrict__ pz,
    short* __restrict__ x2b)
{
    __shared__ float tile[128 * 49];
    const int s = blockIdx.x, tid = threadIdx.x;
    const int b = s / 2304, rr = s % 2304, xx = rr / 48, yy = rr % 48;
    for (int f = tid; f < 6144; f += 256) {
        const int c = f / 48, z = f % 48;
        tile[c * 49 + z] = 2.0f * x[(long)(b * 128 + c) * 110592 + xx * 2304 + yy * 48 + z]
                         + px[c * 48 + xx] + py[c * 48 + yy] + pz[c * 48 + z];
    }
    __syncthreads();
    const long tb = (long)b * 110592 + xx * 2304 + yy * 48;
    for (int f = tid; f < 6144; f += 256) {
        const int t = f >> 7, c = f & 127;
        x2b[(tb + t) * 128 + c] = f2b(tile[c * 49 + t]);
    }
}

// ---------------- MFMA axial attention ------------------------------------------------
template<int AXIS, int ACC>
__global__ __launch_bounds__(256)
void attn_axis(const short* __restrict__ x2b, const short* __restrict__ wcat,
               const short* __restrict__ woutb, const float* __restrict__ bout,
               short* __restrict__ Ab)
{
    __shared__ __align__(16) char SM[60672];
    short* xs  = (short*)SM;              // [48][XSTR] x2 tile; later attn-out O tile
    short* qs  = (short*)(SM + 13056);    // [48][XSTR]
    short* ks  = (short*)(SM + 26112);    // [48][XSTR]
    short* vs  = (short*)(SM + 39168);    // [128][VSTR] V transposed [c][t]
    short* pb  = (short*)(SM + 53504);    // 4 waves x [16][VSTR] P buffer
    float* stg = (float*)(SM + 13056);    // [48][SSTR] fp32 out stage (aliases qs/ks)

    const int tid  = threadIdx.x;
    const int lane = tid & 63;
    const int wave = tid >> 6;
    const int l15  = lane & 15;
    const int quad = lane >> 4;

    const int s = blockIdx.x;
    const int b = s / 2304, rr = s % 2304, u = rr / 48, v = rr % 48;
    long base; int stride;
    if (AXIS == 0)      { base = (long)b * 110592 + u * 48   + v;      stride = 2304; }
    else if (AXIS == 1) { base = (long)b * 110592 + u * 2304 + v;      stride = 48;   }
    else                { base = (long)b * 110592 + u * 2304 + v * 48; stride = 1;    }

    // ---- stage x2 tile ----
    for (int f = tid; f < 1536; f += 256) {
        const int t = f >> 5, c4 = (f & 31) << 2;
        *(short4v*)(xs + t * XSTR + c4) =
            *(const short4v*)(x2b + (base + (long)t * stride) * 128 + c4);
    }
    __syncthreads();

    // ---- q/k/v projection: M=48,N=384,K=128; wave owns 6 n-tiles ----
    short8 af[3][4];
    #pragma unroll
    for (int mt = 0; mt < 3; ++mt)
        #pragma unroll
        for (int k = 0; k < 4; ++k)
            af[mt][k] = *(const short8*)(xs + (mt * 16 + l15) * XSTR + k * 32 + quad * 8);

    for (int nti = 0; nti < 6; ++nti) {
        const int nt = wave * 6 + nti;
        const int n  = nt * 16 + l15;
        short8 bf_[4];
        #pragma unroll
        for (int k = 0; k < 4; ++k)
            bf_[k] = *(const short8*)(wcat + n * 128 + k * 32 + quad * 8);
        floatx4 acc[3] = {{0,0,0,0},{0,0,0,0},{0,0,0,0}};
        #pragma unroll
        for (int mt = 0; mt < 3; ++mt)
            #pragma unroll
            for (int k = 0; k < 4; ++k)
                acc[mt] = __builtin_amdgcn_mfma_f32_16x16x32_bf16(af[mt][k], bf_[k], acc[mt], 0, 0, 0);
        #pragma unroll
        for (int mt = 0; mt < 3; ++mt) {
            const int rbase = mt * 16 + quad * 4;
            if (n < 128) {            // Q (scale folded in)
                #pragma unroll
                for (int g = 0; g < 4; ++g)
                    qs[(rbase + g) * XSTR + n] = f2b(acc[mt][g] * 0.25f);
            } else if (n < 256) {     // K
                #pragma unroll
                for (int g = 0; g < 4; ++g)
                    ks[(rbase + g) * XSTR + (n - 128)] = f2b(acc[mt][g]);
            } else {                  // V, transposed [c][t]: 4 consecutive t -> 8B store
                short4v pk;
                #pragma unroll
                for (int g = 0; g < 4; ++g) pk[g] = f2b(acc[mt][g]);
                *(short4v*)(vs + (n - 256) * VSTR + rbase) = pk;
            }
        }
    }
    __syncthreads();

    // ---- attention: 24 (head, mtile) tasks over 4 waves; softmax in registers ----
    short* pbw = pb + wave * (16 * VSTR);
    const short8 Z8 = {0,0,0,0,0,0,0,0};
    for (int task = wave; task < 24; task += 4) {
        const int h  = task / 3;
        const int mt = task - h * 3;
        const int hb = h * 16;
        // scores S[i][j], K=16 zero-padded to 32
        short8 aq = Z8;
        if (quad < 2) aq = *(const short8*)(qs + (mt * 16 + l15) * XSTR + hb + quad * 8);
        floatx4 sc[3];
        #pragma unroll
        for (int nt = 0; nt < 3; ++nt) {
            short8 bk = Z8;
            if (quad < 2) bk = *(const short8*)(ks + (nt * 16 + l15) * XSTR + hb + quad * 8);
            floatx4 z = {0,0,0,0};
            sc[nt] = __builtin_amdgcn_mfma_f32_16x16x32_bf16(aq, bk, z, 0, 0, 0);
        }
        // per-row softmax: row r=quad*4+g lives in the 16 lanes of this quad
        #pragma unroll
        for (int g = 0; g < 4; ++g) {
            float m = fmaxf(fmaxf(sc[0][g], sc[1][g]), sc[2][g]);
            m = fmaxf(m, __shfl_xor(m, 1, 64));
            m = fmaxf(m, __shfl_xor(m, 2, 64));
            m = fmaxf(m, __shfl_xor(m, 4, 64));
            m = fmaxf(m, __shfl_xor(m, 8, 64));
            const float e0 = __expf(sc[0][g] - m);
            const float e1 = __expf(sc[1][g] - m);
            const float e2 = __expf(sc[2][g] - m);
            float ssum = e0 + e1 + e2;
            ssum += __shfl_xor(ssum, 1, 64);
            ssum += __shfl_xor(ssum, 2, 64);
            ssum += __shfl_xor(ssum, 4, 64);
            ssum += __shfl_xor(ssum, 8, 64);
            const float inv = 1.0f / ssum;
            short* prow = pbw + (quad * 4 + g) * VSTR;
            prow[l15]      = f2b(e0 * inv);
            prow[16 + l15] = f2b(e1 * inv);
            prow[32 + l15] = f2b(e2 * inv);
        }
        // PV: M=16,N=16,K=48 (2 ksteps, second zero-padded)
        floatx4 o = {0,0,0,0};
        {
            short8 ap = *(const short8*)(pbw + l15 * VSTR + quad * 8);
            short8 bv = *(const short8*)(vs + (hb + l15) * VSTR + quad * 8);
            o = __builtin_amdgcn_mfma_f32_16x16x32_bf16(ap, bv, o, 0, 0, 0);
            short8 ap1 = Z8, bv1 = Z8;
            if (quad < 2) {
                ap1 = *(const short8*)(pbw + l15 * VSTR + 32 + quad * 8);
                bv1 = *(const short8*)(vs + (hb + l15) * VSTR + 32 + quad * 8);
            }
            o = __builtin_amdgcn_mfma_f32_16x16x32_bf16(ap1, bv1, o, 0, 0, 0);
        }
        #pragma unroll
        for (int g = 0; g < 4; ++g)
            xs[(mt * 16 + quad * 4 + g) * XSTR + hb + l15] = f2b(o[g]);
    }
    __syncthreads();

    // ---- output projection: M=48,N=128,K=128; wave owns 2 n-tiles ----
    #pragma unroll
    for (int mt = 0; mt < 3; ++mt)
        #pragma unroll
        for (int k = 0; k < 4; ++k)
            af[mt][k] = *(const short8*)(xs + (mt * 16 + l15) * XSTR + k * 32 + quad * 8);

    #pragma unroll
    for (int nth = 0; nth < 2; ++nth) {
        const int nt = wave + nth * 4;
        const int n  = nt * 16 + l15;
        short8 bf_[4];
        #pragma unroll
        for (int k = 0; k < 4; ++k)
            bf_[k] = *(const short8*)(woutb + n * 128 + k * 32 + quad * 8);
        floatx4 acc[3] = {{0,0,0,0},{0,0,0,0},{0,0,0,0}};
        #pragma unroll
        for (int mt = 0; mt < 3; ++mt)
            #pragma unroll
            for (int k = 0; k < 4; ++k)
                acc[mt] = __builtin_amdgcn_mfma_f32_16x16x32_bf16(af[mt][k], bf_[k], acc[mt], 0, 0, 0);
        const float bo = bout[n];
        #pragma unroll
        for (int mt = 0; mt < 3; ++mt)
            #pragma unroll
            for (int g = 0; g < 4; ++g)
                stg[(mt * 16 + quad * 4 + g) * SSTR + n] = acc[mt][g] + bo;
    }
    __syncthreads();

    // ---- coalesced RMW into bf16 A buffer ----
    for (int f = tid; f < 1536; f += 256) {
        const int t = f >> 5, c4 = (f & 31) << 2;
        const long gi = (base + (long)t * stride) * 128 + c4;
        const floatx4 vv = *(const floatx4*)(stg + t * SSTR + c4);
        short4v out4;
        if (ACC) {
            const short4v a4 = *(const short4v*)(Ab + gi);
            #pragma unroll
            for (int i = 0; i < 4; ++i) out4[i] = f2b(b2f(a4[i]) + vv[i]);
        } else {
            #pragma unroll
            for (int i = 0; i < 4; ++i) out4[i] = f2b(vv[i]);
        }
        *(short4v*)(Ab + gi) = out4;
    }
}

// ---------------- residual + LN1 + MLP (MFMA) + LN2 + transpose-out -------------------
static __device__ __forceinline__ void ln_stats(const float* xr, float* mean_,
                                                float* rstd_, int tid)
{
    if (tid < 192) {
        const int r = tid >> 2, p = tid & 3;
        const float* row = xr + r * SSTR + p * 32;
        float s1 = 0.f, s2 = 0.f;
        #pragma unroll
        for (int c = 0; c < 32; ++c) { const float xv = row[c]; s1 += xv; s2 += xv * xv; }
        s1 += __shfl_xor(s1, 1, 64); s1 += __shfl_xor(s1, 2, 64);
        s2 += __shfl_xor(s2, 1, 64); s2 += __shfl_xor(s2, 2, 64);
        if (p == 0) {
            const float m = s1 * (1.f / 128.f);
            mean_[r] = m;
            rstd_[r] = rsqrtf(s2 * (1.f / 128.f) - m * m + 1e-5f);
        }
    }
}

__global__ __launch_bounds__(256)
void mlp_ln(const float* __restrict__ x, const float* __restrict__ px,
            const float* __restrict__ py, const float* __restrict__ pz,
            const short* __restrict__ Ab,
            const float* __restrict__ ln_g, const float* __restrict__ ln_b,
            const short* __restrict__ w1b, const float* __restrict__ b1,
            const short* __restrict__ w2b, const float* __restrict__ b2,
            float* __restrict__ out)
{
    __shared__ __align__(16) char SM2[53888];
    float* xr   = (float*)SM2;               // [48][SSTR] fp32
    short* lnb  = (short*)(SM2 + 25344);     // [48][XSTR]
    short* hbuf = (short*)(SM2 + 38400);     // [48][XSTR]
    float* gs   = (float*)(SM2 + 51456);
    float* bs   = (float*)(SM2 + 51968);
    float* b1s  = (float*)(SM2 + 52480);
    float* b2s  = (float*)(SM2 + 52992);
    float* mean_ = (float*)(SM2 + 53504);
    float* rstd_ = (float*)(SM2 + 53696);

    const int tid  = threadIdx.x;
    const int lane = tid & 63;
    const int wave = tid >> 6;
    const int l15  = lane & 15;
    const int quad = lane >> 4;

    const int s = blockIdx.x;
    const int b = s / 2304, rr = s % 2304, xx = rr / 48, yy = rr % 48;
    const long tb = (long)b * 110592 + xx * 2304 + yy * 48;

    if (tid < 128) {
        gs[tid] = ln_g[tid]; bs[tid] = ln_b[tid];
        b1s[tid] = b1[tid];  b2s[tid] = b2[tid];
    }
    // stage attention sum (bf16, contiguous)
    for (int f = tid; f < 1536; f += 256) {
        const int t = f >> 5, c4 = (f & 31) << 2;
        const short4v a4 = *(const short4v*)(Ab + (tb + t) * 128 + c4);
        #pragma unroll
        for (int i = 0; i < 4; ++i) xr[t * SSTR + c4 + i] = b2f(a4[i]);
    }
    __syncthreads();
    // + fp32-exact x2 recompute
    for (int f = tid; f < 6144; f += 256) {
        const int c = f / 48, z = f % 48;
        xr[z * SSTR + c] += 2.0f * x[(long)(b * 128 + c) * 110592 + xx * 2304 + yy * 48 + z]
                          + px[c * 48 + xx] + py[c * 48 + yy] + pz[c * 48 + z];
    }
    __syncthreads();
    ln_stats(xr, mean_, rstd_, tid);
    __syncthreads();
    for (int f = tid; f < 6144; f += 256) {
        const int t = f >> 7, c = f & 127;
        lnb[t * XSTR + c] = f2b((xr[t * SSTR + c] - mean_[t]) * rstd_[t] * gs[c] + bs[c]);
    }
    __syncthreads();

    // MLP GEMM1: h = relu(ln1 @ w1^T + b1)
    short8 af[3][4];
    #pragma unroll
    for (int mt = 0; mt < 3; ++mt)
        #pragma unroll
        for (int k = 0; k < 4; ++k)
            af[mt][k] = *(const short8*)(lnb + (mt * 16 + l15) * XSTR + k * 32 + quad * 8);
    #pragma unroll
    for (int nth = 0; nth < 2; ++nth) {
        const int nt = wave + nth * 4;
        const int n  = nt * 16 + l15;
        short8 bf_[4];
        #pragma unroll
        for (int k = 0; k < 4; ++k)
            bf_[k] = *(const short8*)(w1b + n * 128 + k * 32 + quad * 8);
        floatx4 acc[3] = {{0,0,0,0},{0,0,0,0},{0,0,0,0}};
        #pragma unroll
        for (int mt = 0; mt < 3; ++mt)
            #pragma unroll
            for (int k = 0; k < 4; ++k)
                acc[mt] = __builtin_amdgcn_mfma_f32_16x16x32_bf16(af[mt][k], bf_[k], acc[mt], 0, 0, 0);
        const float bb = b1s[n];
        #pragma unroll
        for (int mt = 0; mt < 3; ++mt)
            #pragma unroll
            for (int g = 0; g < 4; ++g)
                hbuf[(mt * 16 + quad * 4 + g) * XSTR + n] = f2b(fmaxf(acc[mt][g] + bb, 0.f));
    }
    __syncthreads();

    // MLP GEMM2 + inner residual (fp32-recomputed ln1)
    #pragma unroll
    for (int mt = 0; mt < 3; ++mt)
        #pragma unroll
        for (int k = 0; k < 4; ++k)
            af[mt][k] = *(const short8*)(hbuf + (mt * 16 + l15) * XSTR + k * 32 + quad * 8);
    #pragma unroll
    for (int nth = 0; nth < 2; ++nth) {
        const int nt = wave + nth * 4;
        const int n  = nt * 16 + l15;
        short8 bf_[4];
        #pragma unroll
        for (int k = 0; k < 4; ++k)
            bf_[k] = *(const short8*)(w2b + n * 128 + k * 32 + quad * 8);
        floatx4 acc[3] = {{0,0,0,0},{0,0,0,0},{0,0,0,0}};
        #pragma unroll
        for (int mt = 0; mt < 3; ++mt)
            #pragma unroll
            for (int k = 0; k < 4; ++k)
                acc[mt] = __builtin_amdgcn_mfma_f32_16x16x32_bf16(af[mt][k], bf_[k], acc[mt], 0, 0, 0);
        const float bb = b2s[n];
        #pragma unroll
        for (int mt = 0; mt < 3; ++mt)
            #pragma unroll
            for (int g = 0; g < 4; ++g) {
                const int t = mt * 16 + quad * 4 + g;
                const float ln1 = (xr[t * SSTR + n] - mean_[t]) * rstd_[t] * gs[n] + bs[n];
                xr[t * SSTR + n] = acc[mt][g] + bb + ln1;
            }
    }
    __syncthreads();
    ln_stats(xr, mean_, rstd_, tid);
    __syncthreads();
    // channels-first output
    for (int f = tid; f < 6144; f += 256) {
        const int c = f / 48, z = f % 48;
        out[(long)(b * 128 + c) * 110592 + xx * 2304 + yy * 48 + z] =
            (xr[z * SSTR + c] - mean_[z]) * rstd_[z] * gs[c] + bs[c];
    }
}

// -------------------------------------------------------------------------------------
extern "C" void kernel_launch(void* const* d_in, const int* in_sizes, int n_in,
                              void* d_out, int out_size, void* d_ws, size_t ws_size,
                              hipStream_t stream)
{
    const float* x    = (const float*)d_in[0];
    const float* px   = (const float*)d_in[1];
    const float* py   = (const float*)d_in[2];
    const float* pz   = (const float*)d_in[3];
    const float* wq[3]   = { (const float*)d_in[4],  (const float*)d_in[8],  (const float*)d_in[12] };
    const float* wkv[3]  = { (const float*)d_in[5],  (const float*)d_in[9],  (const float*)d_in[13] };
    const float* wout[3] = { (const float*)d_in[6],  (const float*)d_in[10], (const float*)d_in[14] };
    const float* bout[3] = { (const float*)d_in[7],  (const float*)d_in[11], (const float*)d_in[15] };
    const float* ln_g = (const float*)d_in[16];
    const float* ln_b = (const float*)d_in[17];
    const float* w1   = (const float*)d_in[18];
    const float* b1   = (const float*)d_in[19];
    const float* w2   = (const float*)d_in[20];
    const float* b2   = (const float*)d_in[21];

    // ws layout: A bf16 (56,623,104 B) | weights bf16 (458,752 B) | x2b bf16 (56,623,104 B)
    short* Ab  = (short*)d_ws;
    short* wb  = (short*)((char*)d_ws + 56623104);
    short* x2b = (short*)((char*)d_ws + 57081856);

    prep_weights<<<896, 256, 0, stream>>>(wq[0], wkv[0], wq[1], wkv[1], wq[2], wkv[2],
                                          wout[0], wout[1], wout[2], w1, w2, wb);
    prep_x2<<<4608, 256, 0, stream>>>(x, px, py, pz, x2b);

    attn_axis<0, 0><<<4608, 256, 0, stream>>>(x2b, wb,          wb + 147456,          bout[0], Ab);
    attn_axis<1, 1><<<4608, 256, 0, stream>>>(x2b, wb + 49152,  wb + 147456 + 16384,  bout[1], Ab);
    attn_axis<2, 1><<<4608, 256, 0, stream>>>(x2b, wb + 98304,  wb + 147456 + 32768,  bout[2], Ab);

    mlp_ln<<<4608, 256, 0, stream>>>(x, px, py, pz, Ab, ln_g, ln_b,
                                     wb + 196608, b1, wb + 212992, b2, (float*)d_out);
}

// Round 3
// 761.589 us; speedup vs baseline: 10.2493x; 1.2318x over previous
//
#include <hip/hip_runtime.h>
#include <hip/hip_bf16.h>

typedef __attribute__((ext_vector_type(8))) short short8;
typedef __attribute__((ext_vector_type(4))) short short4v;
typedef __attribute__((ext_vector_type(4))) float floatx4;

#define XSTR 136   // bf16 tile stride (272B rows: 16B-aligned, balanced banks for b128 frags)
#define VSTR 56    // bf16 transposed-V / P stride
#define SSTR 132   // fp32 out-stage stride (attn kernels, vec4-friendly)
#define MSTR 129   // fp32 xr stride in fused kernel (odd word stride -> conflict-free)

static __device__ __forceinline__ short f2b(float f) {
    __hip_bfloat16 h = __float2bfloat16(f);
    return *reinterpret_cast<short*>(&h);
}
static __device__ __forceinline__ float b2f(short s) {
    unsigned int u = ((unsigned int)(unsigned short)s) << 16;
    return __uint_as_float(u);
}

// ---------------- weight cast (keeps [n][k] row-major = MFMA B-operand layout) -------
__global__ __launch_bounds__(256) void prep_weights(
    const float* __restrict__ wq0, const float* __restrict__ wkv0,
    const float* __restrict__ wq1, const float* __restrict__ wkv1,
    const float* __restrict__ wq2, const float* __restrict__ wkv2,
    const float* __restrict__ wout0, const float* __restrict__ wout1,
    const float* __restrict__ wout2, const float* __restrict__ w1,
    const float* __restrict__ w2, short* __restrict__ dst)
{
    const int g = blockIdx.x * 256 + threadIdx.x;  // grid exactly covers 229376
    const float* wqs[3]  = { wq0, wq1, wq2 };
    const float* wkvs[3] = { wkv0, wkv1, wkv2 };
    const float* rest[5] = { wout0, wout1, wout2, w1, w2 };
    float val;
    if (g < 147456) {
        const int a = g / 49152, l = g % 49152;
        val = (l < 16384) ? wqs[a][l] : wkvs[a][l - 16384];
    } else {
        const int l = g - 147456;
        val = rest[l >> 14][l & 16383];
    }
    dst[g] = f2b(val);
}

// ---------------- x2 = 2x + px + py + pz, channels-last bf16 -------------------------
__global__ __launch_bounds__(256) void prep_x2(
    const float* __restrict__ x, const float* __restrict__ px,
    const float* __restrict__ py, const float* __restrict__ pz,
    short* __restrict__ x2b)
{
    __shared__ float tile[128 * 49];
    const int s = blockIdx.x, tid = threadIdx.x;
    const int b = s / 2304, rr = s % 2304, xx = rr / 48, yy = rr % 48;
    for (int f = tid; f < 1536; f += 256) {
        const int c = f / 12, z4 = (f % 12) * 4;
        const floatx4 xv = *(const floatx4*)(x + (long)(b * 128 + c) * 110592 + xx * 2304 + yy * 48 + z4);
        const float pxy = px[c * 48 + xx] + py[c * 48 + yy];
        #pragma unroll
        for (int j = 0; j < 4; ++j)
            tile[c * 49 + z4 + j] = 2.0f * xv[j] + pxy + pz[c * 48 + z4 + j];
    }
    __syncthreads();
    const long tb = (long)b * 110592 + xx * 2304 + yy * 48;
    for (int f = tid; f < 1536; f += 256) {
        const int t = f >> 5, c4 = (f & 31) << 2;
        short4v pk;
        #pragma unroll
        for (int j = 0; j < 4; ++j) pk[j] = f2b(tile[(c4 + j) * 49 + t]);
        *(short4v*)(x2b + (tb + t) * 128 + c4) = pk;
    }
}

// ---------------- MFMA axial attention (axes 0/1) -------------------------------------
template<int AXIS, int ACC>
__global__ __launch_bounds__(256)
void attn_axis(const short* __restrict__ x2b, const short* __restrict__ wcat,
               const short* __restrict__ woutb, const float* __restrict__ bout,
               short* __restrict__ Ab)
{
    __shared__ __align__(16) char SM[60672];
    short* xs  = (short*)SM;              // [48][XSTR] x2 tile; later O tile
    short* qs  = (short*)(SM + 13056);
    short* ks  = (short*)(SM + 26112);
    short* vs  = (short*)(SM + 39168);    // [128][VSTR] V^T
    short* pb  = (short*)(SM + 53504);    // 4 waves x [16][VSTR]
    float* stg = (float*)(SM + 13056);    // [48][SSTR] fp32 out stage (aliases qs/ks)

    const int tid  = threadIdx.x;
    const int lane = tid & 63;
    const int wave = tid >> 6;
    const int l15  = lane & 15;
    const int quad = lane >> 4;

    const int s = blockIdx.x;
    const int b = s / 2304, rr = s % 2304, u = rr / 48, v = rr % 48;
    long base; int stride;
    if (AXIS == 0) { base = (long)b * 110592 + u * 48   + v; stride = 2304; }
    else           { base = (long)b * 110592 + u * 2304 + v; stride = 48;   }

    // ---- prefetch A for the RMW (consumed at the very end) ----
    short4v apre[6];
    if (ACC) {
        #pragma unroll
        for (int i = 0; i < 6; ++i) {
            const int f = tid + i * 256;
            const int t = f >> 5, c4 = (f & 31) << 2;
            apre[i] = *(const short4v*)(Ab + (base + (long)t * stride) * 128 + c4);
        }
    }
    // ---- prefetch first QKV weight frag set (no LDS dependency) ----
    short8 bcur[4], bnext[4];
    {
        const short* wp = wcat + (wave * 96 + l15) * 128 + quad * 8;
        #pragma unroll
        for (int k = 0; k < 4; ++k) bcur[k] = *(const short8*)(wp + k * 32);
    }

    // ---- stage x2 tile ----
    for (int f = tid; f < 1536; f += 256) {
        const int t = f >> 5, c4 = (f & 31) << 2;
        *(short4v*)(xs + t * XSTR + c4) =
            *(const short4v*)(x2b + (base + (long)t * stride) * 128 + c4);
    }
    __syncthreads();

    // ---- q/k/v projection: M=48,N=384,K=128; software-pipelined weight frags ----
    short8 af[3][4];
    #pragma unroll
    for (int mt = 0; mt < 3; ++mt)
        #pragma unroll
        for (int k = 0; k < 4; ++k)
            af[mt][k] = *(const short8*)(xs + (mt * 16 + l15) * XSTR + k * 32 + quad * 8);

    for (int nti = 0; nti < 6; ++nti) {
        const int nt = wave * 6 + nti;
        const int n  = nt * 16 + l15;
        if (nti < 5) {
            const short* wp = wcat + ((nt + 1) * 16 + l15) * 128 + quad * 8;
            #pragma unroll
            for (int k = 0; k < 4; ++k) bnext[k] = *(const short8*)(wp + k * 32);
        }
        floatx4 acc[3] = {{0,0,0,0},{0,0,0,0},{0,0,0,0}};
        #pragma unroll
        for (int mt = 0; mt < 3; ++mt)
            #pragma unroll
            for (int k = 0; k < 4; ++k)
                acc[mt] = __builtin_amdgcn_mfma_f32_16x16x32_bf16(af[mt][k], bcur[k], acc[mt], 0, 0, 0);
        #pragma unroll
        for (int mt = 0; mt < 3; ++mt) {
            const int rbase = mt * 16 + quad * 4;
            if (n < 128) {
                #pragma unroll
                for (int g = 0; g < 4; ++g)
                    qs[(rbase + g) * XSTR + n] = f2b(acc[mt][g] * 0.25f);
            } else if (n < 256) {
                #pragma unroll
                for (int g = 0; g < 4; ++g)
                    ks[(rbase + g) * XSTR + (n - 128)] = f2b(acc[mt][g]);
            } else {
                short4v pk;
                #pragma unroll
                for (int g = 0; g < 4; ++g) pk[g] = f2b(acc[mt][g]);
                *(short4v*)(vs + (n - 256) * VSTR + rbase) = pk;
            }
        }
        #pragma unroll
        for (int k = 0; k < 4; ++k) bcur[k] = bnext[k];
    }
    __syncthreads();

    // ---- attention: 24 (head, mtile) tasks; softmax in registers ----
    short* pbw = pb + wave * (16 * VSTR);
    const short8 Z8 = {0,0,0,0,0,0,0,0};
    for (int task = wave; task < 24; task += 4) {
        const int h  = task / 3;
        const int mt = task - h * 3;
        const int hb = h * 16;
        short8 aq = Z8;
        if (quad < 2) aq = *(const short8*)(qs + (mt * 16 + l15) * XSTR + hb + quad * 8);
        floatx4 sc[3];
        #pragma unroll
        for (int nt = 0; nt < 3; ++nt) {
            short8 bk = Z8;
            if (quad < 2) bk = *(const short8*)(ks + (nt * 16 + l15) * XSTR + hb + quad * 8);
            floatx4 z = {0,0,0,0};
            sc[nt] = __builtin_amdgcn_mfma_f32_16x16x32_bf16(aq, bk, z, 0, 0, 0);
        }
        #pragma unroll
        for (int g = 0; g < 4; ++g) {
            float m = fmaxf(fmaxf(sc[0][g], sc[1][g]), sc[2][g]);
            m = fmaxf(m, __shfl_xor(m, 1, 64));
            m = fmaxf(m, __shfl_xor(m, 2, 64));
            m = fmaxf(m, __shfl_xor(m, 4, 64));
            m = fmaxf(m, __shfl_xor(m, 8, 64));
            const float e0 = __expf(sc[0][g] - m);
            const float e1 = __expf(sc[1][g] - m);
            const float e2 = __expf(sc[2][g] - m);
            float ssum = e0 + e1 + e2;
            ssum += __shfl_xor(ssum, 1, 64);
            ssum += __shfl_xor(ssum, 2, 64);
            ssum += __shfl_xor(ssum, 4, 64);
            ssum += __shfl_xor(ssum, 8, 64);
            const float inv = 1.0f / ssum;
            short* prow = pbw + (quad * 4 + g) * VSTR;
            prow[l15]      = f2b(e0 * inv);
            prow[16 + l15] = f2b(e1 * inv);
            prow[32 + l15] = f2b(e2 * inv);
        }
        floatx4 o = {0,0,0,0};
        {
            short8 ap = *(const short8*)(pbw + l15 * VSTR + quad * 8);
            short8 bv = *(const short8*)(vs + (hb + l15) * VSTR + quad * 8);
            o = __builtin_amdgcn_mfma_f32_16x16x32_bf16(ap, bv, o, 0, 0, 0);
            short8 ap1 = Z8, bv1 = Z8;
            if (quad < 2) {
                ap1 = *(const short8*)(pbw + l15 * VSTR + 32 + quad * 8);
                bv1 = *(const short8*)(vs + (hb + l15) * VSTR + 32 + quad * 8);
            }
            o = __builtin_amdgcn_mfma_f32_16x16x32_bf16(ap1, bv1, o, 0, 0, 0);
        }
        #pragma unroll
        for (int g = 0; g < 4; ++g)
            xs[(mt * 16 + quad * 4 + g) * XSTR + hb + l15] = f2b(o[g]);
    }
    __syncthreads();

    // ---- output projection ----
    #pragma unroll
    for (int mt = 0; mt < 3; ++mt)
        #pragma unroll
        for (int k = 0; k < 4; ++k)
            af[mt][k] = *(const short8*)(xs + (mt * 16 + l15) * XSTR + k * 32 + quad * 8);

    #pragma unroll
    for (int nth = 0; nth < 2; ++nth) {
        const int nt = wave + nth * 4;
        const int n  = nt * 16 + l15;
        short8 bf_[4];
        #pragma unroll
        for (int k = 0; k < 4; ++k)
            bf_[k] = *(const short8*)(woutb + n * 128 + k * 32 + quad * 8);
        floatx4 acc[3] = {{0,0,0,0},{0,0,0,0},{0,0,0,0}};
        #pragma unroll
        for (int mt = 0; mt < 3; ++mt)
            #pragma unroll
            for (int k = 0; k < 4; ++k)
                acc[mt] = __builtin_amdgcn_mfma_f32_16x16x32_bf16(af[mt][k], bf_[k], acc[mt], 0, 0, 0);
        const float bo = bout[n];
        #pragma unroll
        for (int mt = 0; mt < 3; ++mt)
            #pragma unroll
            for (int g = 0; g < 4; ++g)
                stg[(mt * 16 + quad * 4 + g) * SSTR + n] = acc[mt][g] + bo;
    }
    __syncthreads();

    // ---- coalesced write / RMW into bf16 A ----
    #pragma unroll
    for (int i = 0; i < 6; ++i) {
        const int f = tid + i * 256;
        const int t = f >> 5, c4 = (f & 31) << 2;
        const long gi = (base + (long)t * stride) * 128 + c4;
        const floatx4 vv = *(const floatx4*)(stg + t * SSTR + c4);
        short4v out4;
        if (ACC) {
            #pragma unroll
            for (int j = 0; j < 4; ++j) out4[j] = f2b(b2f(apre[i][j]) + vv[j]);
        } else {
            #pragma unroll
            for (int j = 0; j < 4; ++j) out4[j] = f2b(vv[j]);
        }
        *(short4v*)(Ab + gi) = out4;
    }
}

// ---------------- fused axis-2 attention + residual + LN1 + MLP + LN2 + out -----------
static __device__ __forceinline__ void ln_stats129(const float* xr, float* mean_,
                                                   float* rstd_, int tid)
{
    if (tid < 192) {
        const int r = tid >> 2, p = tid & 3;
        const float* row = xr + r * MSTR + p * 32;
        float s1 = 0.f, s2 = 0.f;
        #pragma unroll
        for (int c = 0; c < 32; ++c) { const float xv = row[c]; s1 += xv; s2 += xv * xv; }
        s1 += __shfl_xor(s1, 1, 64); s1 += __shfl_xor(s1, 2, 64);
        s2 += __shfl_xor(s2, 1, 64); s2 += __shfl_xor(s2, 2, 64);
        if (p == 0) {
            const float m = s1 * (1.f / 128.f);
            mean_[r] = m;
            rstd_[r] = rsqrtf(s2 * (1.f / 128.f) - m * m + 1e-5f);
        }
    }
}

__global__ __launch_bounds__(256)
void attn2_mlp(const short* __restrict__ x2b, const short* __restrict__ Ab,
               const short* __restrict__ wcat, const short* __restrict__ woutb,
               const float* __restrict__ bout,
               const float* __restrict__ ln_g, const float* __restrict__ ln_b,
               const short* __restrict__ w1b, const float* __restrict__ b1,
               const short* __restrict__ w2b, const float* __restrict__ b2,
               float* __restrict__ out)
{
    __shared__ __align__(16) char SM[76160];
    short* xs   = (short*)SM;              // x2 tile, live whole kernel (residual)
    short* qs   = (short*)(SM + 13056);
    short* ks   = (short*)(SM + 26112);
    short* vs   = (short*)(SM + 39168);    // 14336
    short* pb   = (short*)(SM + 53504);    // 7168
    short* ob   = (short*)(SM + 60672);    // O tile, 13056
    float* xr   = (float*)(SM + 13056);    // [48][MSTR] fp32 (aliases qs+ks)
    short* lnb  = (short*)(SM + 39168);    // aliases vs
    short* hbuf = (short*)(SM + 60672);    // aliases ob
    float* gs   = (float*)(SM + 73728);
    float* bs   = (float*)(SM + 74240);
    float* b1s  = (float*)(SM + 74752);
    float* b2s  = (float*)(SM + 75264);
    float* mean_ = (float*)(SM + 75776);
    float* rstd_ = (float*)(SM + 75968);

    const int tid  = threadIdx.x;
    const int lane = tid & 63;
    const int wave = tid >> 6;
    const int l15  = lane & 15;
    const int quad = lane >> 4;

    const int s = blockIdx.x;
    const int b = s / 2304, rr = s % 2304, xx = rr / 48, yy = rr % 48;
    const long tb = (long)b * 110592 + xx * 2304 + yy * 48;

    // ---- prefetch attention-sum A (consumed after out-proj) ----
    short4v apre[6];
    #pragma unroll
    for (int i = 0; i < 6; ++i) {
        const int f = tid + i * 256;
        const int t = f >> 5, c4 = (f & 31) << 2;
        apre[i] = *(const short4v*)(Ab + (tb + t) * 128 + c4);
    }
    // ---- prefetch first QKV weight frag set ----
    short8 bcur[4], bnext[4];
    {
        const short* wp = wcat + (wave * 96 + l15) * 128 + quad * 8;
        #pragma unroll
        for (int k = 0; k < 4; ++k) bcur[k] = *(const short8*)(wp + k * 32);
    }

    if (tid < 128) {
        gs[tid] = ln_g[tid]; bs[tid] = ln_b[tid];
        b1s[tid] = b1[tid];  b2s[tid] = b2[tid];
    }
    // ---- stage x2 tile (fully contiguous for z-axis) ----
    for (int f = tid; f < 1536; f += 256) {
        const int t = f >> 5, c4 = (f & 31) << 2;
        *(short4v*)(xs + t * XSTR + c4) = *(const short4v*)(x2b + (tb + t) * 128 + c4);
    }
    __syncthreads();

    // ---- QKV projection ----
    short8 af[3][4];
    #pragma unroll
    for (int mt = 0; mt < 3; ++mt)
        #pragma unroll
        for (int k = 0; k < 4; ++k)
            af[mt][k] = *(const short8*)(xs + (mt * 16 + l15) * XSTR + k * 32 + quad * 8);

    for (int nti = 0; nti < 6; ++nti) {
        const int nt = wave * 6 + nti;
        const int n  = nt * 16 + l15;
        if (nti < 5) {
            const short* wp = wcat + ((nt + 1) * 16 + l15) * 128 + quad * 8;
            #pragma unroll
            for (int k = 0; k < 4; ++k) bnext[k] = *(const short8*)(wp + k * 32);
        }
        floatx4 acc[3] = {{0,0,0,0},{0,0,0,0},{0,0,0,0}};
        #pragma unroll
        for (int mt = 0; mt < 3; ++mt)
            #pragma unroll
            for (int k = 0; k < 4; ++k)
                acc[mt] = __builtin_amdgcn_mfma_f32_16x16x32_bf16(af[mt][k], bcur[k], acc[mt], 0, 0, 0);
        #pragma unroll
        for (int mt = 0; mt < 3; ++mt) {
            const int rbase = mt * 16 + quad * 4;
            if (n < 128) {
                #pragma unroll
                for (int g = 0; g < 4; ++g)
                    qs[(rbase + g) * XSTR + n] = f2b(acc[mt][g] * 0.25f);
            } else if (n < 256) {
                #pragma unroll
                for (int g = 0; g < 4; ++g)
                    ks[(rbase + g) * XSTR + (n - 128)] = f2b(acc[mt][g]);
            } else {
                short4v pk;
                #pragma unroll
                for (int g = 0; g < 4; ++g) pk[g] = f2b(acc[mt][g]);
                *(short4v*)(vs + (n - 256) * VSTR + rbase) = pk;
            }
        }
        #pragma unroll
        for (int k = 0; k < 4; ++k) bcur[k] = bnext[k];
    }
    __syncthreads();

    // ---- attention tasks (O -> ob) ----
    short* pbw = pb + wave * (16 * VSTR);
    const short8 Z8 = {0,0,0,0,0,0,0,0};
    for (int task = wave; task < 24; task += 4) {
        const int h  = task / 3;
        const int mt = task - h * 3;
        const int hb = h * 16;
        short8 aq = Z8;
        if (quad < 2) aq = *(const short8*)(qs + (mt * 16 + l15) * XSTR + hb + quad * 8);
        floatx4 sc[3];
        #pragma unroll
        for (int nt = 0; nt < 3; ++nt) {
            short8 bk = Z8;
            if (quad < 2) bk = *(const short8*)(ks + (nt * 16 + l15) * XSTR + hb + quad * 8);
            floatx4 z = {0,0,0,0};
            sc[nt] = __builtin_amdgcn_mfma_f32_16x16x32_bf16(aq, bk, z, 0, 0, 0);
        }
        #pragma unroll
        for (int g = 0; g < 4; ++g) {
            float m = fmaxf(fmaxf(sc[0][g], sc[1][g]), sc[2][g]);
            m = fmaxf(m, __shfl_xor(m, 1, 64));
            m = fmaxf(m, __shfl_xor(m, 2, 64));
            m = fmaxf(m, __shfl_xor(m, 4, 64));
            m = fmaxf(m, __shfl_xor(m, 8, 64));
            const float e0 = __expf(sc[0][g] - m);
            const float e1 = __expf(sc[1][g] - m);
            const float e2 = __expf(sc[2][g] - m);
            float ssum = e0 + e1 + e2;
            ssum += __shfl_xor(ssum, 1, 64);
            ssum += __shfl_xor(ssum, 2, 64);
            ssum += __shfl_xor(ssum, 4, 64);
            ssum += __shfl_xor(ssum, 8, 64);
            const float inv = 1.0f / ssum;
            short* prow = pbw + (quad * 4 + g) * VSTR;
            prow[l15]      = f2b(e0 * inv);
            prow[16 + l15] = f2b(e1 * inv);
            prow[32 + l15] = f2b(e2 * inv);
        }
        floatx4 o = {0,0,0,0};
        {
            short8 ap = *(const short8*)(pbw + l15 * VSTR + quad * 8);
            short8 bv = *(const short8*)(vs + (hb + l15) * VSTR + quad * 8);
            o = __builtin_amdgcn_mfma_f32_16x16x32_bf16(ap, bv, o, 0, 0, 0);
            short8 ap1 = Z8, bv1 = Z8;
            if (quad < 2) {
                ap1 = *(const short8*)(pbw + l15 * VSTR + 32 + quad * 8);
                bv1 = *(const short8*)(vs + (hb + l15) * VSTR + 32 + quad * 8);
            }
            o = __builtin_amdgcn_mfma_f32_16x16x32_bf16(ap1, bv1, o, 0, 0, 0);
        }
        #pragma unroll
        for (int g = 0; g < 4; ++g)
            ob[(mt * 16 + quad * 4 + g) * XSTR + hb + l15] = f2b(o[g]);
    }
    __syncthreads();

    // ---- output projection -> xr (fp32, + bias) ----
    #pragma unroll
    for (int mt = 0; mt < 3; ++mt)
        #pragma unroll
        for (int k = 0; k < 4; ++k)
            af[mt][k] = *(const short8*)(ob + (mt * 16 + l15) * XSTR + k * 32 + quad * 8);
    #pragma unroll
    for (int nth = 0; nth < 2; ++nth) {
        const int nt = wave + nth * 4;
        const int n  = nt * 16 + l15;
        short8 bf_[4];
        #pragma unroll
        for (int k = 0; k < 4; ++k)
            bf_[k] = *(const short8*)(woutb + n * 128 + k * 32 + quad * 8);
        floatx4 acc[3] = {{0,0,0,0},{0,0,0,0},{0,0,0,0}};
        #pragma unroll
        for (int mt = 0; mt < 3; ++mt)
            #pragma unroll
            for (int k = 0; k < 4; ++k)
                acc[mt] = __builtin_amdgcn_mfma_f32_16x16x32_bf16(af[mt][k], bf_[k], acc[mt], 0, 0, 0);
        const float bo = bout[n];
        #pragma unroll
        for (int mt = 0; mt < 3; ++mt)
            #pragma unroll
            for (int g = 0; g < 4; ++g)
                xr[(mt * 16 + quad * 4 + g) * MSTR + n] = acc[mt][g] + bo;
    }
    __syncthreads();

    // ---- residual: xr += A(prefetched) + x2(LDS) ----
    #pragma unroll
    for (int i = 0; i < 6; ++i) {
        const int f = tid + i * 256;
        const int t = f >> 5, c4 = (f & 31) << 2;
        #pragma unroll
        for (int j = 0; j < 4; ++j)
            xr[t * MSTR + c4 + j] += b2f(apre[i][j]) + b2f(xs[t * XSTR + c4 + j]);
    }
    __syncthreads();

    ln_stats129(xr, mean_, rstd_, tid);
    __syncthreads();
    for (int f = tid; f < 6144; f += 256) {
        const int t = f >> 7, c = f & 127;
        lnb[t * XSTR + c] = f2b((xr[t * MSTR + c] - mean_[t]) * rstd_[t] * gs[c] + bs[c]);
    }
    __syncthreads();

    // ---- MLP GEMM1 + relu ----
    #pragma unroll
    for (int mt = 0; mt < 3; ++mt)
        #pragma unroll
        for (int k = 0; k < 4; ++k)
            af[mt][k] = *(const short8*)(lnb + (mt * 16 + l15) * XSTR + k * 32 + quad * 8);
    #pragma unroll
    for (int nth = 0; nth < 2; ++nth) {
        const int nt = wave + nth * 4;
        const int n  = nt * 16 + l15;
        short8 bf_[4];
        #pragma unroll
        for (int k = 0; k < 4; ++k)
            bf_[k] = *(const short8*)(w1b + n * 128 + k * 32 + quad * 8);
        floatx4 acc[3] = {{0,0,0,0},{0,0,0,0},{0,0,0,0}};
        #pragma unroll
        for (int mt = 0; mt < 3; ++mt)
            #pragma unroll
            for (int k = 0; k < 4; ++k)
                acc[mt] = __builtin_amdgcn_mfma_f32_16x16x32_bf16(af[mt][k], bf_[k], acc[mt], 0, 0, 0);
        const float bb = b1s[n];
        #pragma unroll
        for (int mt = 0; mt < 3; ++mt)
            #pragma unroll
            for (int g = 0; g < 4; ++g)
                hbuf[(mt * 16 + quad * 4 + g) * XSTR + n] = f2b(fmaxf(acc[mt][g] + bb, 0.f));
    }
    __syncthreads();

    // ---- MLP GEMM2 + inner residual (fp32-recomputed ln1) ----
    #pragma unroll
    for (int mt = 0; mt < 3; ++mt)
        #pragma unroll
        for (int k = 0; k < 4; ++k)
            af[mt][k] = *(const short8*)(hbuf + (mt * 16 + l15) * XSTR + k * 32 + quad * 8);
    #pragma unroll
    for (int nth = 0; nth < 2; ++nth) {
        const int nt = wave + nth * 4;
        const int n  = nt * 16 + l15;
        short8 bf_[4];
        #pragma unroll
        for (int k = 0; k < 4; ++k)
            bf_[k] = *(const short8*)(w2b + n * 128 + k * 32 + quad * 8);
        floatx4 acc[3] = {{0,0,0,0},{0,0,0,0},{0,0,0,0}};
        #pragma unroll
        for (int mt = 0; mt < 3; ++mt)
            #pragma unroll
            for (int k = 0; k < 4; ++k)
                acc[mt] = __builtin_amdgcn_mfma_f32_16x16x32_bf16(af[mt][k], bf_[k], acc[mt], 0, 0, 0);
        const float bb = b2s[n];
        #pragma unroll
        for (int mt = 0; mt < 3; ++mt)
            #pragma unroll
            for (int g = 0; g < 4; ++g) {
                const int t = mt * 16 + quad * 4 + g;
                const float ln1 = (xr[t * MSTR + n] - mean_[t]) * rstd_[t] * gs[n] + bs[n];
                xr[t * MSTR + n] = acc[mt][g] + bb + ln1;
            }
    }
    __syncthreads();
    ln_stats129(xr, mean_, rstd_, tid);
    __syncthreads();

    // ---- channels-first vectorized output ----
    for (int f = tid; f < 1536; f += 256) {
        const int c = f / 12, z4 = (f % 12) * 4;
        floatx4 o4;
        #pragma unroll
        for (int j = 0; j < 4; ++j)
            o4[j] = (xr[(z4 + j) * MSTR + c] - mean_[z4 + j]) * rstd_[z4 + j] * gs[c] + bs[c];
        *(floatx4*)(out + (long)(b * 128 + c) * 110592 + xx * 2304 + yy * 48 + z4) = o4;
    }
}

// -------------------------------------------------------------------------------------
extern "C" void kernel_launch(void* const* d_in, const int* in_sizes, int n_in,
                              void* d_out, int out_size, void* d_ws, size_t ws_size,
                              hipStream_t stream)
{
    const float* x    = (const float*)d_in[0];
    const float* px   = (const float*)d_in[1];
    const float* py   = (const float*)d_in[2];
    const float* pz   = (const float*)d_in[3];
    const float* wq[3]   = { (const float*)d_in[4],  (const float*)d_in[8],  (const float*)d_in[12] };
    const float* wkv[3]  = { (const float*)d_in[5],  (const float*)d_in[9],  (const float*)d_in[13] };
    const float* wout[3] = { (const float*)d_in[6],  (const float*)d_in[10], (const float*)d_in[14] };
    const float* bout[3] = { (const float*)d_in[7],  (const float*)d_in[11], (const float*)d_in[15] };
    const float* ln_g = (const float*)d_in[16];
    const float* ln_b = (const float*)d_in[17];
    const float* w1   = (const float*)d_in[18];
    const float* b1   = (const float*)d_in[19];
    const float* w2   = (const float*)d_in[20];
    const float* b2   = (const float*)d_in[21];

    // ws: A bf16 (56,623,104 B) | weights bf16 (458,752 B) | x2b bf16 (56,623,104 B)
    short* Ab  = (short*)d_ws;
    short* wb  = (short*)((char*)d_ws + 56623104);
    short* x2b = (short*)((char*)d_ws + 57081856);

    prep_weights<<<896, 256, 0, stream>>>(wq[0], wkv[0], wq[1], wkv[1], wq[2], wkv[2],
                                          wout[0], wout[1], wout[2], w1, w2, wb);
    prep_x2<<<4608, 256, 0, stream>>>(x, px, py, pz, x2b);

    attn_axis<0, 0><<<4608, 256, 0, stream>>>(x2b, wb,         wb + 147456, bout[0], Ab);
    attn_axis<1, 1><<<4608, 256, 0, stream>>>(x2b, wb + 49152, wb + 163840, bout[1], Ab);

    attn2_mlp<<<4608, 256, 0, stream>>>(x2b, Ab, wb + 98304, wb + 180224, bout[2],
                                        ln_g, ln_b, wb + 196608, b1, wb + 212992, b2,
                                        (float*)d_out);
}